// Round 9
// baseline (169.578 us; speedup 1.0000x reference)
//
#include <hip/hip_runtime.h>
#include <hip/hip_bf16.h>
#include <math.h>
#include <string.h>

#define P 65536   // H*W
#define HH 256
#define WW 256

typedef __attribute__((ext_vector_type(8))) short bf16x8;
typedef __attribute__((ext_vector_type(4))) float f32x4;

__device__ __forceinline__ float fast_sigmoid(float v) {
    return 1.f / (1.f + __expf(-v));
}
__device__ __forceinline__ float fast_tanh(float a) {
    a = fminf(fmaxf(a, -10.f), 10.f);
    float t = __expf(2.f * a);
    return (t - 1.f) / (t + 1.f);
}
__device__ __forceinline__ ushort f2bf(float f) {
    unsigned u = __float_as_uint(f);
    unsigned r = (u + 0x7fffu + ((u >> 16) & 1u)) >> 16;
    return (ushort)r;
}
__device__ __forceinline__ unsigned pack_bf2(float a, float b) {
    __hip_bfloat162 h = __float22bfloat162_rn(make_float2(a, b));
    unsigned u;
    memcpy(&u, &h, 4);
    return u;
}

// ---------------------------------------------------------------------------
// setup_k: blocks [0,512) convert F1/pan NCHW f32 -> NHWC bf16; blocks
// [512,812) run weight-prep.
// Float region W (21248):
//   [0,2304)       aue_wt  [ci64][k9][co4]
//   [2304,6400)    s1w1t   [ci64][co64]
//   [6400,10496)   s1w2t   [ci64][co64]
//   [10496,14592)  s2w1t   [ci64][co64]
//   [14592,18688)  s2w2t   [ci64][co64]
//   [18688,21248)  mw      [t10][o4][c64]
// ushort region wub (55296):
//   [0,18432)      wbfu    [ct4][kp9][n16][ci32]  (ue conv B frags)
//   [18432,36864)  w2bf1   [mo32][K576] K=k*64+n  (cw1 @ ua1, bf16)
//   [36864,55296)  w2bf2   [mo32][K576]           (cw2 @ ua2, bf16)
__global__ __launch_bounds__(256) void setup_k(
        const float* __restrict__ F1, const float* __restrict__ pan,
        ushort* __restrict__ xbf, ushort* __restrict__ panbf,
        const float* __restrict__ ue_w, const float* __restrict__ aue_w,
        const float* __restrict__ ua1, const float* __restrict__ ua2,
        const float* __restrict__ s1w1, const float* __restrict__ s1w2,
        const float* __restrict__ s2w1, const float* __restrict__ s2w2,
        const float* __restrict__ cw1, const float* __restrict__ cw2,
        const float* __restrict__ masks_u, const float* __restrict__ w4,
        float* __restrict__ W, ushort* __restrict__ wub) {
    const int b = blockIdx.x;
    if (b < 512) {
        int idx = b * 256 + threadIdx.x;
        const float* src = (idx < P) ? F1 : pan;
        ushort* dst = (idx < P) ? xbf : panbf;
        int p = idx & (P - 1);
        unsigned pk[16];
        #pragma unroll
        for (int c = 0; c < 16; ++c) {
            float a = src[(2 * c) * P + p];
            float bb = src[(2 * c + 1) * P + p];
            pk[c] = (unsigned)f2bf(a) | ((unsigned)f2bf(bb) << 16);
        }
        uint4* d4 = (uint4*)(dst + (size_t)p * 32);
        #pragma unroll
        for (int q = 0; q < 4; ++q)
            d4[q] = make_uint4(pk[4 * q], pk[4 * q + 1], pk[4 * q + 2], pk[4 * q + 3]);
        return;
    }
    int i = (b - 512) * 256 + threadIdx.x;
    if (i < 2304) {                        // aue_w (co4, ci64, 9) -> [ci][k][co]
        int ci = i / 36, r = i % 36, k = r >> 2, co = r & 3;
        W[i] = aue_w[co * 576 + ci * 9 + k];
    } else if (i < 6400) {
        int j = i - 2304;  W[i] = s1w1[(j & 63) * 64 + (j >> 6)];
    } else if (i < 10496) {
        int j = i - 6400;  W[i] = s1w2[(j & 63) * 64 + (j >> 6)];
    } else if (i < 14592) {
        int j = i - 10496; W[i] = s2w1[(j & 63) * 64 + (j >> 6)];
    } else if (i < 18688) {
        int j = i - 14592; W[i] = s2w2[(j & 63) * 64 + (j >> 6)];
    } else if (i < 21248) {                // mw[t][o][c]
        int j = i - 18688;
        int t = j >> 8, o = (j >> 6) & 3, c = j & 63;
        W[i] = (masks_u[t * 64 + c] < 0.8f) ? w4[o * 64 + c] : 0.f;
    } else if (i < 39680) {                // wbfu
        int j = i - 21248;
        int ct = j / 4608, r1 = j % 4608;
        int kp = r1 / 512, r2 = r1 % 512;
        int n = r2 >> 5, ci = r2 & 31;
        wub[j] = f2bf(ue_w[(ct * 16 + n) * 288 + ci * 9 + kp]);
    } else if (i < 58112) {                // w2bf1 = cw1 @ ua1
        int j = i - 39680;
        int mo = j / 576, K = j % 576, k = K >> 6, n = K & 63;
        float s = 0.f;
        for (int m = 0; m < 32; ++m)
            s += cw1[mo * 32 + m] * ua1[m * 576 + n * 9 + k];
        wub[18432 + j] = f2bf(s);
    } else if (i < 76544) {                // w2bf2 = cw2 @ ua2
        int j = i - 58112;
        int mo = j / 576, K = j % 576, k = K >> 6, n = K & 63;
        float s = 0.f;
        for (int m = 0; m < 32; ++m)
            s += cw2[mo * 32 + m] * ua2[m * 576 + n * 9 + k];
        wub[36864 + j] = f2bf(s);
    }
}

// ---------------------------------------------------------------------------
// ue conv (32->64, 3x3, pad=1) as MFMA implicit GEMM. Output: NHWC bf16.
__global__ __launch_bounds__(256) void conv_ue_mfma(
        const ushort* __restrict__ xbf, const ushort* __restrict__ wbfu,
        const float* __restrict__ bias, ushort* __restrict__ xnh) {
    __shared__ float tls[4][272];
    const int tid  = threadIdx.x;
    const int lane = tid & 63;
    const int wv   = __builtin_amdgcn_readfirstlane(tid >> 6);
    const int lrow = lane & 15;
    const int kg   = lane >> 4;

    bf16x8 zf;
    #pragma unroll
    for (int z = 0; z < 8; ++z) zf[z] = 0;

    bf16x8 Bf[9];
    const ushort* wb = wbfu + wv * 4608;
    #pragma unroll
    for (int kp = 0; kp < 9; ++kp)
        Bf[kp] = *(const bf16x8*)(wb + kp * 512 + lrow * 32 + kg * 8);

    const float bco = bias[wv * 16 + lrow];
    float* tw = tls[wv];

    for (int si = 0; si < 4; ++si) {
        const int s   = blockIdx.x * 4 + si;
        const int row = s >> 4;
        const int cb  = (s & 15) << 4;
        const int pb  = s << 4;
        f32x4 acc = {bco, bco, bco, bco};
        #pragma unroll
        for (int dh = -1; dh <= 1; ++dh) {
            if ((unsigned)(row + dh) >= 256u) continue;
            #pragma unroll
            for (int dw = -1; dw <= 1; ++dw) {
                const bool kill = (dw == -1 && cb == 0 && lrow == 0) ||
                                  (dw == 1 && cb == 240 && lrow == 15);
                const int apx = kill ? pb : (pb + dh * 256 + dw + lrow);
                bf16x8 Af = *(const bf16x8*)(xbf + (size_t)apx * 32 + kg * 8);
                if (kill) Af = zf;
                acc = __builtin_amdgcn_mfma_f32_16x16x32_bf16(
                          Af, Bf[(dh + 1) * 3 + (dw + 1)], acc, 0, 0, 0);
            }
        }
        #pragma unroll
        for (int j = 0; j < 4; ++j)
            tw[(kg * 4 + j) * 17 + lrow] = acc[j];
        asm volatile("s_waitcnt lgkmcnt(0)" ::: "memory");
        {
            const float* rp = tw + lrow * 17;
            unsigned o[8];
            #pragma unroll
            for (int q = 0; q < 8; ++q)
                o[q] = pack_bf2(rp[2 * q], rp[2 * q + 1]);
            ushort* dst = xnh + (size_t)(pb + lrow) * 64 + wv * 16;
            *(uint4*)dst       = make_uint4(o[0], o[1], o[2], o[3]);
            *(uint4*)(dst + 8) = make_uint4(o[4], o[5], o[6], o[7]);
        }
        asm volatile("s_waitcnt lgkmcnt(0)" ::: "memory");
    }
}

// ---------------------------------------------------------------------------
// Fused head: AU = sigmoid(conv3x3(x;64->4)), EU/MEAN = var/mean of xs.
__global__ __launch_bounds__(256) void head_k(
        const ushort* __restrict__ xnh, const float* __restrict__ aue_wt,
        const float* __restrict__ aue_b, const float* __restrict__ mw,
        const float* __restrict__ b4, const float* __restrict__ msin,
        float* __restrict__ AU, float* __restrict__ EU, float* __restrict__ MEAN) {
    __shared__ float cs[64][65];
    __shared__ float pr[4][4][64];
    const int tid = threadIdx.x;
    const int pxg = tid & 63;
    const int g   = __builtin_amdgcn_readfirstlane(tid >> 6);
    const int p   = blockIdx.x * 64 + pxg;
    const int h = p >> 8, x0 = p & 255;
    const int cib = g * 16;

    float pa[4] = {0.f, 0.f, 0.f, 0.f};
    float cv[16];
    #pragma unroll
    for (int k = 0; k < 9; ++k) {
        const int dh = k / 3 - 1, dw = k % 3 - 1;
        if ((unsigned)(h + dh) >= 256u) continue;
        const bool kill = (dw == -1 && x0 == 0) || (dw == 1 && x0 == 255);
        const int pxe = kill ? p : (p + dh * 256 + dw);
        const ushort* sp = xnh + (size_t)pxe * 64 + cib;
        uint4 ra = *(const uint4*)sp;
        uint4 rb = *(const uint4*)(sp + 8);
        unsigned rr[8] = {ra.x, ra.y, ra.z, ra.w, rb.x, rb.y, rb.z, rb.w};
        if (kill) {
            #pragma unroll
            for (int q = 0; q < 8; ++q) rr[q] = 0;
        }
        float f[16];
        #pragma unroll
        for (int q = 0; q < 8; ++q) {
            f[2 * q]     = __uint_as_float(rr[q] << 16);
            f[2 * q + 1] = __uint_as_float(rr[q] & 0xffff0000u);
        }
        if (k == 4) {
            #pragma unroll
            for (int ci = 0; ci < 16; ++ci) cv[ci] = f[ci];
        }
        #pragma unroll
        for (int ci = 0; ci < 16; ++ci) {
            const float* wp = aue_wt + (cib + ci) * 36 + k * 4;
            #pragma unroll
            for (int co = 0; co < 4; ++co)
                pa[co] = fmaf(f[ci], wp[co], pa[co]);
        }
    }
    #pragma unroll
    for (int co = 0; co < 4; ++co) pr[co][g][pxg] = pa[co];
    #pragma unroll
    for (int ci = 0; ci < 16; ++ci) cs[pxg][cib + ci] = cv[ci];
    __syncthreads();

    {
        float s = aue_b[g] + pr[g][0][pxg] + pr[g][1][pxg]
                           + pr[g][2][pxg] + pr[g][3][pxg];
        AU[g * P + p] = fast_sigmoid(s);
    }

    float xv[64];
    #pragma unroll
    for (int c = 0; c < 64; ++c) xv[c] = cs[pxg][c];
    float msv = msin[g * P + p];
    float bo  = b4[g];
    float vals[10];
    float s = 0.f;
    #pragma unroll
    for (int t = 0; t < 10; ++t) {
        float a = bo;
        const float* mwp = mw + t * 256 + g * 64;
        #pragma unroll
        for (int c = 0; c < 64; ++c) a = fmaf(mwp[c], xv[c], a);
        float v = fast_tanh(a) + msv;
        vals[t] = v;
        s += v;
    }
    float m = s * 0.1f;
    MEAN[g * P + p] = m;
    float var = 0.f;
    #pragma unroll
    for (int t = 0; t < 10; ++t) { float d = vals[t] - m; var = fmaf(d, d, var); }
    EU[g * P + p] = var * (1.0f / 9.0f);
}

// ---------------------------------------------------------------------------
// Fully fused uaconv: gates (spe MLP + spa chain) -> LDS -> MFMA einsum with
// folded 1x1. Block = 64 px; phase 1 computes spec[64px][64ch] and
// spat[9][64px] in LDS; phase 2 = per-wave 16-px MFMA strips.
// OUTMODE 0: f2 NHWC bf16; OUTMODE 1: FOUT f32 CHW.
template<int OUTMODE>
__global__ __launch_bounds__(256) void ua_fused_k(
        const float* __restrict__ U, int flip,
        const float* __restrict__ aw0, const float* __restrict__ ab0,
        const float* __restrict__ aw1, const float* __restrict__ ab1,
        const float* __restrict__ aw2, const float* __restrict__ ab2,
        const float* __restrict__ pw0, const float* __restrict__ pb0,
        const float* __restrict__ pw1t, const float* __restrict__ pb1,
        const float* __restrict__ pw2t, const float* __restrict__ pb2,
        const ushort* __restrict__ xa, const ushort* __restrict__ xb,
        const ushort* __restrict__ w2bf, const float* __restrict__ cb,
        float* __restrict__ outf, ushort* __restrict__ outh) {
    __shared__ float h2s[64 * 64];      // 16 KB (phase 1 only)
    __shared__ float spec_l[64][68];    // 17 KB
    __shared__ float spat_l[9][64];     // 2.25 KB
    __shared__ float tls[4][560];       // 8.75 KB (phase 2 epilogue)
    const int tid = threadIdx.x;
    const int pxg = tid & 63;
    const int g   = __builtin_amdgcn_readfirstlane(tid >> 6);
    const int cbase = g * 16;
    const int p   = blockIdx.x * 64 + pxg;
    const int h = p >> 8, x0 = p & 255;

    // ================= phase 1: gates =================
    {
        float u[4];
        #pragma unroll
        for (int ci = 0; ci < 4; ++ci) {
            float v = U[ci * P + p];
            u[ci] = flip ? 1.f - v : v;
        }
        float h2[16];
        #pragma unroll
        for (int j = 0; j < 16; ++j) h2[j] = pb1[cbase + j];
        #pragma unroll 8
        for (int ci = 0; ci < 64; ++ci) {
            float s = pb0[ci];
            #pragma unroll
            for (int k = 0; k < 4; ++k) s = fmaf(u[k], pw0[ci * 4 + k], s);
            float hv = fmaxf(s, 0.f);
            const float* wr = pw1t + ci * 64 + cbase;    // uniform -> s_load
            #pragma unroll
            for (int j = 0; j < 16; ++j) h2[j] = fmaf(hv, wr[j], h2[j]);
        }
        #pragma unroll
        for (int j = 0; j < 16; ++j)
            h2s[(cbase + j) * 64 + pxg] = fmaxf(h2[j], 0.f);
        __syncthreads();

        float h3[16];
        #pragma unroll
        for (int j = 0; j < 16; ++j) h3[j] = pb2[cbase + j];
        #pragma unroll 8
        for (int ci = 0; ci < 64; ++ci) {
            float hv = h2s[ci * 64 + pxg];
            const float* wr = pw2t + ci * 64 + cbase;    // uniform -> s_load
            #pragma unroll
            for (int j = 0; j < 16; ++j) h3[j] = fmaf(hv, wr[j], h3[j]);
        }
        #pragma unroll
        for (int j = 0; j < 16; ++j)
            spec_l[pxg][cbase + j] = fast_sigmoid(h3[j]);

        // spa (this wave's co subset)
        float uh[4][9];
        #pragma unroll
        for (int ci = 0; ci < 4; ++ci) {
            const float* up = U + ci * P;
            #pragma unroll
            for (int kh = 0; kh < 3; ++kh) {
                int hh = h + kh - 1;
                bool hok = (unsigned)hh < 256u;
                #pragma unroll
                for (int kw = 0; kw < 3; ++kw) {
                    int wx = x0 + kw - 1;
                    bool ok = hok && (unsigned)wx < 256u;
                    float v = ok ? up[hh * WW + wx] : 0.f;
                    if (flip && ok) v = 1.f - v;
                    uh[ci][kh * 3 + kw] = v;
                }
            }
        }
        float a1[9];
        #pragma unroll
        for (int co = 0; co < 9; ++co) {
            float s = ab0[co];
            #pragma unroll
            for (int ci = 0; ci < 4; ++ci)
                #pragma unroll
                for (int k = 0; k < 9; ++k)
                    s = fmaf(uh[ci][k], aw0[co * 36 + ci * 9 + k], s);
            a1[co] = fmaxf(s, 0.f);
        }
        float a2[9];
        #pragma unroll
        for (int co = 0; co < 9; ++co) {
            float s = ab1[co];
            #pragma unroll
            for (int ci = 0; ci < 9; ++ci) s = fmaf(a1[ci], aw1[co * 9 + ci], s);
            a2[co] = fmaxf(s, 0.f);
        }
        #pragma unroll
        for (int cq = 0; cq < 3; ++cq) {
            const int co = g + cq * 4;
            if (co < 9) {
                float s = ab2[co];
                #pragma unroll
                for (int ci = 0; ci < 9; ++ci) s = fmaf(a2[ci], aw2[co * 9 + ci], s);
                spat_l[co][pxg] = fast_sigmoid(s);
            }
        }
    }
    __syncthreads();

    // ================= phase 2: MFMA einsum =================
    const int lane = tid & 63;
    const int lrow = lane & 15;
    const int kg   = lane >> 4;
    const int wv   = g;
    const int s    = blockIdx.x * 4 + wv;
    const int row  = s >> 4;
    const int c16  = s & 15;
    const int pb   = s << 4;
    const int px   = pb + lrow;
    const int pxl  = wv * 16 + lrow;    // local pixel index

    float sl[8], sh[8];
    {
        const float* sp = &spec_l[pxl][kg * 8];
        #pragma unroll
        for (int j = 0; j < 8; ++j) sl[j] = sp[j];
        const float* sp2 = &spec_l[pxl][32 + kg * 8];
        #pragma unroll
        for (int j = 0; j < 8; ++j) sh[j] = sp2[j];
    }
    const ushort* b0p = w2bf + lrow * 576 + kg * 8;
    const ushort* b1p = w2bf + (16 + lrow) * 576 + kg * 8;

    f32x4 acc0 = {0.f, 0.f, 0.f, 0.f};
    f32x4 acc1 = {0.f, 0.f, 0.f, 0.f};

    #pragma unroll
    for (int k = 0; k < 9; ++k) {
        const int dh = k / 3 - 1, dw = k % 3 - 1;
        if ((unsigned)(row + dh) >= 256u) continue;   // wave-uniform skip
        const bool kill = (dw == -1 && c16 == 0 && lrow == 0) ||
                          (dw == 1 && c16 == 15 && lrow == 15);
        float stk = spat_l[k][pxl];
        if (kill) stk = 0.f;
        const int pxe = kill ? px : (px + dh * 256 + dw);
        #pragma unroll
        for (int par = 0; par < 2; ++par) {
            const ushort* src = (par == 0) ? (xa + (size_t)pxe * 32 + kg * 8)
                                           : (xb + (size_t)pxe * 32 + kg * 8);
            uint4 raw = *(const uint4*)src;
            const float* ss = par ? sh : sl;
            unsigned rr[4] = {raw.x, raw.y, raw.z, raw.w};
            union { unsigned u[4]; bf16x8 v; } af;
            #pragma unroll
            for (int q = 0; q < 4; ++q) {
                float e0 = __uint_as_float(rr[q] << 16)          * (ss[2 * q] * stk);
                float e1 = __uint_as_float(rr[q] & 0xffff0000u)  * (ss[2 * q + 1] * stk);
                af.u[q] = pack_bf2(e0, e1);
            }
            const int ki = k * 2 + par;
            bf16x8 bf0 = *(const bf16x8*)(b0p + ki * 32);
            bf16x8 bf1 = *(const bf16x8*)(b1p + ki * 32);
            acc0 = __builtin_amdgcn_mfma_f32_16x16x32_bf16(af.v, bf0, acc0, 0, 0, 0);
            acc1 = __builtin_amdgcn_mfma_f32_16x16x32_bf16(af.v, bf1, acc1, 0, 0, 0);
        }
    }

    const float cb0 = cb[lrow], cb1 = cb[16 + lrow];
    float* tw = tls[wv];
    #pragma unroll
    for (int j = 0; j < 4; ++j) {
        float y0 = acc0[j] + cb0; y0 = y0 > 0.f ? y0 : 0.2f * y0;
        float y1 = acc1[j] + cb1; y1 = y1 > 0.f ? y1 : 0.2f * y1;
        tw[(kg * 4 + j) * 35 + lrow] = y0;
        tw[(kg * 4 + j) * 35 + 16 + lrow] = y1;
    }
    asm volatile("s_waitcnt lgkmcnt(0)" ::: "memory");
    if constexpr (OUTMODE == 0) {
        const float* rp = tw + lrow * 35 + kg * 8;
        unsigned o[4];
        #pragma unroll
        for (int q = 0; q < 4; ++q)
            o[q] = pack_bf2(rp[2 * q], rp[2 * q + 1]);
        *(uint4*)(outh + (size_t)(pb + lrow) * 32 + kg * 8) =
            make_uint4(o[0], o[1], o[2], o[3]);
    } else {
        #pragma unroll
        for (int it = 0; it < 8; ++it) {
            const int mo = kg * 8 + it;
            outf[mo * P + pb + lrow] = tw[lrow * 35 + mo];
        }
    }
    asm volatile("s_waitcnt lgkmcnt(0)" ::: "memory");
}

// ---------------------------------------------------------------------------
extern "C" void kernel_launch(void* const* d_in, const int* in_sizes, int n_in,
                              void* d_out, int out_size, void* d_ws, size_t ws_size,
                              hipStream_t stream) {
    const float* F1        = (const float*)d_in[0];
    const float* ms        = (const float*)d_in[1];
    const float* pan       = (const float*)d_in[2];
    const float* masks_u   = (const float*)d_in[3];
    const float* ue_conv_w = (const float*)d_in[4];
    const float* ue_conv_b = (const float*)d_in[5];
    const float* ue_out_w  = (const float*)d_in[6];
    const float* ue_out_b  = (const float*)d_in[7];
    const float* ue_aue_w  = (const float*)d_in[8];
    const float* ue_aue_b  = (const float*)d_in[9];
    const float* conv1_w   = (const float*)d_in[10];
    const float* conv1_b   = (const float*)d_in[11];
    const float* conv2_w   = (const float*)d_in[12];
    const float* conv2_b   = (const float*)d_in[13];
    const float* spa1_w0 = (const float*)d_in[14];
    const float* spa1_b0 = (const float*)d_in[15];
    const float* spa1_w1 = (const float*)d_in[16];
    const float* spa1_b1 = (const float*)d_in[17];
    const float* spa1_w2 = (const float*)d_in[18];
    const float* spa1_b2 = (const float*)d_in[19];
    const float* spe1_w0 = (const float*)d_in[20];
    const float* spe1_b0 = (const float*)d_in[21];
    const float* spe1_w1 = (const float*)d_in[22];
    const float* spe1_b1 = (const float*)d_in[23];
    const float* spe1_w2 = (const float*)d_in[24];
    const float* spe1_b2 = (const float*)d_in[25];
    const float* ua1_w   = (const float*)d_in[26];
    const float* spa2_w0 = (const float*)d_in[27];
    const float* spa2_b0 = (const float*)d_in[28];
    const float* spa2_w1 = (const float*)d_in[29];
    const float* spa2_b1 = (const float*)d_in[30];
    const float* spa2_w2 = (const float*)d_in[31];
    const float* spa2_b2 = (const float*)d_in[32];
    const float* spe2_w0 = (const float*)d_in[33];
    const float* spe2_b0 = (const float*)d_in[34];
    const float* spe2_w1 = (const float*)d_in[35];
    const float* spe2_b1 = (const float*)d_in[36];
    const float* spe2_w2 = (const float*)d_in[37];
    const float* spe2_b2 = (const float*)d_in[38];
    const float* ua2_w   = (const float*)d_in[39];

    float* out  = (float*)d_out;
    float* AU   = out;             // 4*P
    float* EU   = out + 4 * P;     // 4*P
    float* MEAN = out + 8 * P;     // 4*P
    float* FOUT = out + 12 * P;    // 32*P

    float* ws    = (float*)d_ws;
    ushort* xbf   = (ushort*)ws;                // 32P bf16 (16P f32)
    ushort* panbf = (ushort*)(ws + 16 * P);     // 32P bf16
    ushort* xnh   = (ushort*)(ws + 32 * P);     // 64P bf16 NHWC (32P f32)
    ushort* f2nh  = (ushort*)(ws + 64 * P);     // 32P bf16 (16P f32)
    float* W     = ws + 80 * P;                 // weight tables
    float* aue_wt = W;
    float* s1w1t  = W + 2304;
    float* s1w2t  = W + 6400;
    float* s2w1t  = W + 10496;
    float* s2w2t  = W + 14592;
    float* mw     = W + 18688;
    ushort* wub   = (ushort*)(W + 21248);
    ushort* wbfu  = wub;
    ushort* w2bf1 = wub + 18432;
    ushort* w2bf2 = wub + 36864;

    dim3 blk(256);

    setup_k<<<dim3(812), blk, 0, stream>>>(F1, pan, xbf, panbf,
                                           ue_conv_w, ue_aue_w, ua1_w, ua2_w,
                                           spe1_w1, spe1_w2, spe2_w1, spe2_w2,
                                           conv1_w, conv2_w, masks_u, ue_out_w, W, wub);

    // x = conv3x3(F_1; 32->64) via MFMA, NHWC bf16 out
    conv_ue_mfma<<<dim3(1024), blk, 0, stream>>>(xbf, wbfu, ue_conv_b, xnh);
    // Fused head: AU + EU + MEAN
    head_k<<<dim3(1024), blk, 0, stream>>>(xnh, aue_wt, ue_aue_b, mw, ue_out_b, ms,
                                           AU, EU, MEAN);

    // ---- uaconv 1 (U = EU, inputs F1 || pan) + folded conv1 -> f2 bf16 ----
    ua_fused_k<0><<<dim3(1024), blk, 0, stream>>>(
        EU, 0,
        spa1_w0, spa1_b0, spa1_w1, spa1_b1, spa1_w2, spa1_b2,
        spe1_w0, spe1_b0, s1w1t, spe1_b1, s1w2t, spe1_b2,
        xbf, panbf, w2bf1, conv1_b, nullptr, f2nh);

    // ---- uaconv 2 (U = 1-EU, inputs F1 || F_2) + folded conv2 -> FOUT ----
    ua_fused_k<1><<<dim3(1024), blk, 0, stream>>>(
        EU, 1,
        spa2_w0, spa2_b0, spa2_w1, spa2_b1, spa2_w2, spa2_b2,
        spe2_w0, spe2_b0, s2w1t, spe2_b1, s2w2t, spe2_b2,
        xbf, f2nh, w2bf2, conv2_b, FOUT, nullptr);
}

// Round 10
// 133.374 us; speedup vs baseline: 1.2715x; 1.2715x over previous
//
#include <hip/hip_runtime.h>
#include <hip/hip_bf16.h>
#include <math.h>
#include <string.h>

#define P 65536   // H*W
#define HH 256
#define WW 256

typedef __attribute__((ext_vector_type(8))) short bf16x8;
typedef __attribute__((ext_vector_type(4))) float f32x4;

__device__ __forceinline__ float fast_sigmoid(float v) {
    return 1.f / (1.f + __expf(-v));
}
__device__ __forceinline__ float fast_tanh(float a) {
    a = fminf(fmaxf(a, -10.f), 10.f);
    float t = __expf(2.f * a);
    return (t - 1.f) / (t + 1.f);
}
__device__ __forceinline__ ushort f2bf(float f) {
    unsigned u = __float_as_uint(f);
    unsigned r = (u + 0x7fffu + ((u >> 16) & 1u)) >> 16;
    return (ushort)r;
}
__device__ __forceinline__ unsigned pack_bf2(float a, float b) {
    __hip_bfloat162 h = __float22bfloat162_rn(make_float2(a, b));
    unsigned u;
    memcpy(&u, &h, 4);
    return u;
}

// ---------------------------------------------------------------------------
// setup_k: blocks [0,512) convert F1/pan NCHW f32 -> NHWC bf16; blocks
// [512,812) run weight-prep. (layouts documented in R8/R9)
__global__ __launch_bounds__(256) void setup_k(
        const float* __restrict__ F1, const float* __restrict__ pan,
        ushort* __restrict__ xbf, ushort* __restrict__ panbf,
        const float* __restrict__ ue_w, const float* __restrict__ aue_w,
        const float* __restrict__ ua1, const float* __restrict__ ua2,
        const float* __restrict__ s1w1, const float* __restrict__ s1w2,
        const float* __restrict__ s2w1, const float* __restrict__ s2w2,
        const float* __restrict__ cw1, const float* __restrict__ cw2,
        const float* __restrict__ masks_u, const float* __restrict__ w4,
        float* __restrict__ W, ushort* __restrict__ wub) {
    const int b = blockIdx.x;
    if (b < 512) {
        int idx = b * 256 + threadIdx.x;
        const float* src = (idx < P) ? F1 : pan;
        ushort* dst = (idx < P) ? xbf : panbf;
        int p = idx & (P - 1);
        unsigned pk[16];
        #pragma unroll
        for (int c = 0; c < 16; ++c) {
            float a = src[(2 * c) * P + p];
            float bb = src[(2 * c + 1) * P + p];
            pk[c] = (unsigned)f2bf(a) | ((unsigned)f2bf(bb) << 16);
        }
        uint4* d4 = (uint4*)(dst + (size_t)p * 32);
        #pragma unroll
        for (int q = 0; q < 4; ++q)
            d4[q] = make_uint4(pk[4 * q], pk[4 * q + 1], pk[4 * q + 2], pk[4 * q + 3]);
        return;
    }
    int i = (b - 512) * 256 + threadIdx.x;
    if (i < 2304) {                        // aue_w (co4, ci64, 9) -> [ci][k][co]
        int ci = i / 36, r = i % 36, k = r >> 2, co = r & 3;
        W[i] = aue_w[co * 576 + ci * 9 + k];
    } else if (i < 6400) {
        int j = i - 2304;  W[i] = s1w1[(j & 63) * 64 + (j >> 6)];
    } else if (i < 10496) {
        int j = i - 6400;  W[i] = s1w2[(j & 63) * 64 + (j >> 6)];
    } else if (i < 14592) {
        int j = i - 10496; W[i] = s2w1[(j & 63) * 64 + (j >> 6)];
    } else if (i < 18688) {
        int j = i - 14592; W[i] = s2w2[(j & 63) * 64 + (j >> 6)];
    } else if (i < 21248) {                // mw[t][o][c]
        int j = i - 18688;
        int t = j >> 8, o = (j >> 6) & 3, c = j & 63;
        W[i] = (masks_u[t * 64 + c] < 0.8f) ? w4[o * 64 + c] : 0.f;
    } else if (i < 39680) {                // wbfu
        int j = i - 21248;
        int ct = j / 4608, r1 = j % 4608;
        int kp = r1 / 512, r2 = r1 % 512;
        int n = r2 >> 5, ci = r2 & 31;
        wub[j] = f2bf(ue_w[(ct * 16 + n) * 288 + ci * 9 + kp]);
    } else if (i < 58112) {                // w2bf1 = cw1 @ ua1
        int j = i - 39680;
        int mo = j / 576, K = j % 576, k = K >> 6, n = K & 63;
        float s = 0.f;
        for (int m = 0; m < 32; ++m)
            s += cw1[mo * 32 + m] * ua1[m * 576 + n * 9 + k];
        wub[18432 + j] = f2bf(s);
    } else if (i < 76544) {                // w2bf2 = cw2 @ ua2
        int j = i - 58112;
        int mo = j / 576, K = j % 576, k = K >> 6, n = K & 63;
        float s = 0.f;
        for (int m = 0; m < 32; ++m)
            s += cw2[mo * 32 + m] * ua2[m * 576 + n * 9 + k];
        wub[36864 + j] = f2bf(s);
    }
}

// ---------------------------------------------------------------------------
// ue conv (32->64, 3x3, pad=1) as MFMA implicit GEMM. Output: NHWC bf16.
__global__ __launch_bounds__(256) void conv_ue_mfma(
        const ushort* __restrict__ xbf, const ushort* __restrict__ wbfu,
        const float* __restrict__ bias, ushort* __restrict__ xnh) {
    __shared__ float tls[4][272];
    const int tid  = threadIdx.x;
    const int lane = tid & 63;
    const int wv   = __builtin_amdgcn_readfirstlane(tid >> 6);
    const int lrow = lane & 15;
    const int kg   = lane >> 4;

    bf16x8 zf;
    #pragma unroll
    for (int z = 0; z < 8; ++z) zf[z] = 0;

    bf16x8 Bf[9];
    const ushort* wb = wbfu + wv * 4608;
    #pragma unroll
    for (int kp = 0; kp < 9; ++kp)
        Bf[kp] = *(const bf16x8*)(wb + kp * 512 + lrow * 32 + kg * 8);

    const float bco = bias[wv * 16 + lrow];
    float* tw = tls[wv];

    for (int si = 0; si < 4; ++si) {
        const int s   = blockIdx.x * 4 + si;
        const int row = s >> 4;
        const int cb  = (s & 15) << 4;
        const int pb  = s << 4;
        f32x4 acc = {bco, bco, bco, bco};
        #pragma unroll
        for (int dh = -1; dh <= 1; ++dh) {
            if ((unsigned)(row + dh) >= 256u) continue;
            #pragma unroll
            for (int dw = -1; dw <= 1; ++dw) {
                const bool kill = (dw == -1 && cb == 0 && lrow == 0) ||
                                  (dw == 1 && cb == 240 && lrow == 15);
                const int apx = kill ? pb : (pb + dh * 256 + dw + lrow);
                bf16x8 Af = *(const bf16x8*)(xbf + (size_t)apx * 32 + kg * 8);
                if (kill) Af = zf;
                acc = __builtin_amdgcn_mfma_f32_16x16x32_bf16(
                          Af, Bf[(dh + 1) * 3 + (dw + 1)], acc, 0, 0, 0);
            }
        }
        #pragma unroll
        for (int j = 0; j < 4; ++j)
            tw[(kg * 4 + j) * 17 + lrow] = acc[j];
        asm volatile("s_waitcnt lgkmcnt(0)" ::: "memory");
        {
            const float* rp = tw + lrow * 17;
            unsigned o[8];
            #pragma unroll
            for (int q = 0; q < 8; ++q)
                o[q] = pack_bf2(rp[2 * q], rp[2 * q + 1]);
            ushort* dst = xnh + (size_t)(pb + lrow) * 64 + wv * 16;
            *(uint4*)dst       = make_uint4(o[0], o[1], o[2], o[3]);
            *(uint4*)(dst + 8) = make_uint4(o[4], o[5], o[6], o[7]);
        }
        asm volatile("s_waitcnt lgkmcnt(0)" ::: "memory");
    }
}

// ---------------------------------------------------------------------------
// Fused head: AU = sigmoid(conv3x3(x;64->4)), EU/MEAN = var/mean of xs.
__global__ __launch_bounds__(256) void head_k(
        const ushort* __restrict__ xnh, const float* __restrict__ aue_wt,
        const float* __restrict__ aue_b, const float* __restrict__ mw,
        const float* __restrict__ b4, const float* __restrict__ msin,
        float* __restrict__ AU, float* __restrict__ EU, float* __restrict__ MEAN) {
    __shared__ float cs[64][65];
    __shared__ float pr[4][4][64];
    const int tid = threadIdx.x;
    const int pxg = tid & 63;
    const int g   = __builtin_amdgcn_readfirstlane(tid >> 6);
    const int p   = blockIdx.x * 64 + pxg;
    const int h = p >> 8, x0 = p & 255;
    const int cib = g * 16;

    float pa[4] = {0.f, 0.f, 0.f, 0.f};
    float cv[16];
    #pragma unroll
    for (int k = 0; k < 9; ++k) {
        const int dh = k / 3 - 1, dw = k % 3 - 1;
        if ((unsigned)(h + dh) >= 256u) continue;
        const bool kill = (dw == -1 && x0 == 0) || (dw == 1 && x0 == 255);
        const int pxe = kill ? p : (p + dh * 256 + dw);
        const ushort* sp = xnh + (size_t)pxe * 64 + cib;
        uint4 ra = *(const uint4*)sp;
        uint4 rb = *(const uint4*)(sp + 8);
        unsigned rr[8] = {ra.x, ra.y, ra.z, ra.w, rb.x, rb.y, rb.z, rb.w};
        if (kill) {
            #pragma unroll
            for (int q = 0; q < 8; ++q) rr[q] = 0;
        }
        float f[16];
        #pragma unroll
        for (int q = 0; q < 8; ++q) {
            f[2 * q]     = __uint_as_float(rr[q] << 16);
            f[2 * q + 1] = __uint_as_float(rr[q] & 0xffff0000u);
        }
        if (k == 4) {
            #pragma unroll
            for (int ci = 0; ci < 16; ++ci) cv[ci] = f[ci];
        }
        #pragma unroll
        for (int ci = 0; ci < 16; ++ci) {
            const float* wp = aue_wt + (cib + ci) * 36 + k * 4;
            #pragma unroll
            for (int co = 0; co < 4; ++co)
                pa[co] = fmaf(f[ci], wp[co], pa[co]);
        }
    }
    #pragma unroll
    for (int co = 0; co < 4; ++co) pr[co][g][pxg] = pa[co];
    #pragma unroll
    for (int ci = 0; ci < 16; ++ci) cs[pxg][cib + ci] = cv[ci];
    __syncthreads();

    {
        float s = aue_b[g] + pr[g][0][pxg] + pr[g][1][pxg]
                           + pr[g][2][pxg] + pr[g][3][pxg];
        AU[g * P + p] = fast_sigmoid(s);
    }

    float xv[64];
    #pragma unroll
    for (int c = 0; c < 64; ++c) xv[c] = cs[pxg][c];
    float msv = msin[g * P + p];
    float bo  = b4[g];
    float vals[10];
    float s = 0.f;
    #pragma unroll
    for (int t = 0; t < 10; ++t) {
        float a = bo;
        const float* mwp = mw + t * 256 + g * 64;
        #pragma unroll
        for (int c = 0; c < 64; ++c) a = fmaf(mwp[c], xv[c], a);
        float v = fast_tanh(a) + msv;
        vals[t] = v;
        s += v;
    }
    float m = s * 0.1f;
    MEAN[g * P + p] = m;
    float var = 0.f;
    #pragma unroll
    for (int t = 0; t < 10; ++t) { float d = vals[t] - m; var = fmaf(d, d, var); }
    EU[g * P + p] = var * (1.0f / 9.0f);
}

// ---------------------------------------------------------------------------
// Fully fused uaconv, LDS-dieted: sbuf unions phase-1 h2s (16KB) with the
// phase-2 epilogue tile; spec stored as packed bf16 pairs [64][40] uints
// (b128-aligned rows). Total LDS ~28.9 KB -> 5 blocks/CU.
// OUTMODE 0: f2 NHWC bf16; OUTMODE 1: FOUT f32 CHW.
template<int OUTMODE>
__global__ __launch_bounds__(256) void ua_fused_k(
        const float* __restrict__ U, int flip,
        const float* __restrict__ aw0, const float* __restrict__ ab0,
        const float* __restrict__ aw1, const float* __restrict__ ab1,
        const float* __restrict__ aw2, const float* __restrict__ ab2,
        const float* __restrict__ pw0, const float* __restrict__ pb0,
        const float* __restrict__ pw1t, const float* __restrict__ pb1,
        const float* __restrict__ pw2t, const float* __restrict__ pb2,
        const ushort* __restrict__ xa, const ushort* __restrict__ xb,
        const ushort* __restrict__ w2bf, const float* __restrict__ cb,
        float* __restrict__ outf, ushort* __restrict__ outh) {
    __shared__ float sbuf[64 * 64];       // phase1: h2s [ci][px]; phase2: tls [4][560]
    __shared__ unsigned spec_lu[64][40];  // [px][n/2] packed bf16x2, 10.2 KB
    __shared__ float spat_l[9][64];       // 2.25 KB
    const int tid = threadIdx.x;
    const int pxg = tid & 63;
    const int g   = __builtin_amdgcn_readfirstlane(tid >> 6);
    const int cbase = g * 16;
    const int p   = blockIdx.x * 64 + pxg;
    const int h = p >> 8, x0 = p & 255;

    // ================= phase 1: gates =================
    {
        float u[4];
        #pragma unroll
        for (int ci = 0; ci < 4; ++ci) {
            float v = U[ci * P + p];
            u[ci] = flip ? 1.f - v : v;
        }
        float h2[16];
        #pragma unroll
        for (int j = 0; j < 16; ++j) h2[j] = pb1[cbase + j];
        #pragma unroll 8
        for (int ci = 0; ci < 64; ++ci) {
            float s = pb0[ci];
            #pragma unroll
            for (int k = 0; k < 4; ++k) s = fmaf(u[k], pw0[ci * 4 + k], s);
            float hv = fmaxf(s, 0.f);
            const float* wr = pw1t + ci * 64 + cbase;    // uniform -> s_load
            #pragma unroll
            for (int j = 0; j < 16; ++j) h2[j] = fmaf(hv, wr[j], h2[j]);
        }
        #pragma unroll
        for (int j = 0; j < 16; ++j)
            sbuf[(cbase + j) * 64 + pxg] = fmaxf(h2[j], 0.f);
        __syncthreads();

        float h3[16];
        #pragma unroll
        for (int j = 0; j < 16; ++j) h3[j] = pb2[cbase + j];
        #pragma unroll 8
        for (int ci = 0; ci < 64; ++ci) {
            float hv = sbuf[ci * 64 + pxg];
            const float* wr = pw2t + ci * 64 + cbase;    // uniform -> s_load
            #pragma unroll
            for (int j = 0; j < 16; ++j) h3[j] = fmaf(hv, wr[j], h3[j]);
        }
        #pragma unroll
        for (int q = 0; q < 8; ++q)
            spec_lu[pxg][(cbase >> 1) + q] =
                pack_bf2(fast_sigmoid(h3[2 * q]), fast_sigmoid(h3[2 * q + 1]));

        // spa (this wave's co subset)
        float uh[4][9];
        #pragma unroll
        for (int ci = 0; ci < 4; ++ci) {
            const float* up = U + ci * P;
            #pragma unroll
            for (int kh = 0; kh < 3; ++kh) {
                int hh = h + kh - 1;
                bool hok = (unsigned)hh < 256u;
                #pragma unroll
                for (int kw = 0; kw < 3; ++kw) {
                    int wx = x0 + kw - 1;
                    bool ok = hok && (unsigned)wx < 256u;
                    float v = ok ? up[hh * WW + wx] : 0.f;
                    if (flip && ok) v = 1.f - v;
                    uh[ci][kh * 3 + kw] = v;
                }
            }
        }
        float a1[9];
        #pragma unroll
        for (int co = 0; co < 9; ++co) {
            float s = ab0[co];
            #pragma unroll
            for (int ci = 0; ci < 4; ++ci)
                #pragma unroll
                for (int k = 0; k < 9; ++k)
                    s = fmaf(uh[ci][k], aw0[co * 36 + ci * 9 + k], s);
            a1[co] = fmaxf(s, 0.f);
        }
        float a2[9];
        #pragma unroll
        for (int co = 0; co < 9; ++co) {
            float s = ab1[co];
            #pragma unroll
            for (int ci = 0; ci < 9; ++ci) s = fmaf(a1[ci], aw1[co * 9 + ci], s);
            a2[co] = fmaxf(s, 0.f);
        }
        #pragma unroll
        for (int cq = 0; cq < 3; ++cq) {
            const int co = g + cq * 4;
            if (co < 9) {
                float s = ab2[co];
                #pragma unroll
                for (int ci = 0; ci < 9; ++ci) s = fmaf(a2[ci], aw2[co * 9 + ci], s);
                spat_l[co][pxg] = fast_sigmoid(s);
            }
        }
    }
    __syncthreads();   // phase1 done; sbuf re-purposed as epilogue tile below

    // ================= phase 2: MFMA einsum =================
    const int lane = tid & 63;
    const int lrow = lane & 15;
    const int kg   = lane >> 4;
    const int wv   = g;
    const int s    = blockIdx.x * 4 + wv;
    const int row  = s >> 4;
    const int c16  = s & 15;
    const int pb   = s << 4;
    const int px   = pb + lrow;
    const int pxl  = wv * 16 + lrow;    // local pixel index

    float sl[8], sh[8];
    {
        const unsigned* sp = &spec_lu[pxl][kg * 4];
        #pragma unroll
        for (int q = 0; q < 4; ++q) {
            unsigned uu = sp[q];
            sl[2 * q]     = __uint_as_float(uu << 16);
            sl[2 * q + 1] = __uint_as_float(uu & 0xffff0000u);
        }
        const unsigned* sp2 = &spec_lu[pxl][16 + kg * 4];
        #pragma unroll
        for (int q = 0; q < 4; ++q) {
            unsigned uu = sp2[q];
            sh[2 * q]     = __uint_as_float(uu << 16);
            sh[2 * q + 1] = __uint_as_float(uu & 0xffff0000u);
        }
    }
    const ushort* b0p = w2bf + lrow * 576 + kg * 8;
    const ushort* b1p = w2bf + (16 + lrow) * 576 + kg * 8;

    f32x4 acc0 = {0.f, 0.f, 0.f, 0.f};
    f32x4 acc1 = {0.f, 0.f, 0.f, 0.f};

    #pragma unroll
    for (int k = 0; k < 9; ++k) {
        const int dh = k / 3 - 1, dw = k % 3 - 1;
        if ((unsigned)(row + dh) >= 256u) continue;   // wave-uniform skip
        const bool kill = (dw == -1 && c16 == 0 && lrow == 0) ||
                          (dw == 1 && c16 == 15 && lrow == 15);
        float stk = spat_l[k][pxl];
        if (kill) stk = 0.f;
        const int pxe = kill ? px : (px + dh * 256 + dw);
        #pragma unroll
        for (int par = 0; par < 2; ++par) {
            const ushort* src = (par == 0) ? (xa + (size_t)pxe * 32 + kg * 8)
                                           : (xb + (size_t)pxe * 32 + kg * 8);
            uint4 raw = *(const uint4*)src;
            const float* ss = par ? sh : sl;
            unsigned rr[4] = {raw.x, raw.y, raw.z, raw.w};
            union { unsigned u[4]; bf16x8 v; } af;
            #pragma unroll
            for (int q = 0; q < 4; ++q) {
                float e0 = __uint_as_float(rr[q] << 16)          * (ss[2 * q] * stk);
                float e1 = __uint_as_float(rr[q] & 0xffff0000u)  * (ss[2 * q + 1] * stk);
                af.u[q] = pack_bf2(e0, e1);
            }
            const int ki = k * 2 + par;
            bf16x8 bf0 = *(const bf16x8*)(b0p + ki * 32);
            bf16x8 bf1 = *(const bf16x8*)(b1p + ki * 32);
            acc0 = __builtin_amdgcn_mfma_f32_16x16x32_bf16(af.v, bf0, acc0, 0, 0, 0);
            acc1 = __builtin_amdgcn_mfma_f32_16x16x32_bf16(af.v, bf1, acc1, 0, 0, 0);
        }
    }

    const float cb0 = cb[lrow], cb1 = cb[16 + lrow];
    float* tw = sbuf + wv * 560;
    #pragma unroll
    for (int j = 0; j < 4; ++j) {
        float y0 = acc0[j] + cb0; y0 = y0 > 0.f ? y0 : 0.2f * y0;
        float y1 = acc1[j] + cb1; y1 = y1 > 0.f ? y1 : 0.2f * y1;
        tw[(kg * 4 + j) * 35 + lrow] = y0;
        tw[(kg * 4 + j) * 35 + 16 + lrow] = y1;
    }
    asm volatile("s_waitcnt lgkmcnt(0)" ::: "memory");
    if constexpr (OUTMODE == 0) {
        const float* rp = tw + lrow * 35 + kg * 8;
        unsigned o[4];
        #pragma unroll
        for (int q = 0; q < 4; ++q)
            o[q] = pack_bf2(rp[2 * q], rp[2 * q + 1]);
        *(uint4*)(outh + (size_t)(pb + lrow) * 32 + kg * 8) =
            make_uint4(o[0], o[1], o[2], o[3]);
    } else {
        #pragma unroll
        for (int it = 0; it < 8; ++it) {
            const int mo = kg * 8 + it;
            outf[mo * P + pb + lrow] = tw[lrow * 35 + mo];
        }
    }
    asm volatile("s_waitcnt lgkmcnt(0)" ::: "memory");
}

// ---------------------------------------------------------------------------
extern "C" void kernel_launch(void* const* d_in, const int* in_sizes, int n_in,
                              void* d_out, int out_size, void* d_ws, size_t ws_size,
                              hipStream_t stream) {
    const float* F1        = (const float*)d_in[0];
    const float* ms        = (const float*)d_in[1];
    const float* pan       = (const float*)d_in[2];
    const float* masks_u   = (const float*)d_in[3];
    const float* ue_conv_w = (const float*)d_in[4];
    const float* ue_conv_b = (const float*)d_in[5];
    const float* ue_out_w  = (const float*)d_in[6];
    const float* ue_out_b  = (const float*)d_in[7];
    const float* ue_aue_w  = (const float*)d_in[8];
    const float* ue_aue_b  = (const float*)d_in[9];
    const float* conv1_w   = (const float*)d_in[10];
    const float* conv1_b   = (const float*)d_in[11];
    const float* conv2_w   = (const float*)d_in[12];
    const float* conv2_b   = (const float*)d_in[13];
    const float* spa1_w0 = (const float*)d_in[14];
    const float* spa1_b0 = (const float*)d_in[15];
    const float* spa1_w1 = (const float*)d_in[16];
    const float* spa1_b1 = (const float*)d_in[17];
    const float* spa1_w2 = (const float*)d_in[18];
    const float* spa1_b2 = (const float*)d_in[19];
    const float* spe1_w0 = (const float*)d_in[20];
    const float* spe1_b0 = (const float*)d_in[21];
    const float* spe1_w1 = (const float*)d_in[22];
    const float* spe1_b1 = (const float*)d_in[23];
    const float* spe1_w2 = (const float*)d_in[24];
    const float* spe1_b2 = (const float*)d_in[25];
    const float* ua1_w   = (const float*)d_in[26];
    const float* spa2_w0 = (const float*)d_in[27];
    const float* spa2_b0 = (const float*)d_in[28];
    const float* spa2_w1 = (const float*)d_in[29];
    const float* spa2_b1 = (const float*)d_in[30];
    const float* spa2_w2 = (const float*)d_in[31];
    const float* spa2_b2 = (const float*)d_in[32];
    const float* spe2_w0 = (const float*)d_in[33];
    const float* spe2_b0 = (const float*)d_in[34];
    const float* spe2_w1 = (const float*)d_in[35];
    const float* spe2_b1 = (const float*)d_in[36];
    const float* spe2_w2 = (const float*)d_in[37];
    const float* spe2_b2 = (const float*)d_in[38];
    const float* ua2_w   = (const float*)d_in[39];

    float* out  = (float*)d_out;
    float* AU   = out;             // 4*P
    float* EU   = out + 4 * P;     // 4*P
    float* MEAN = out + 8 * P;     // 4*P
    float* FOUT = out + 12 * P;    // 32*P

    float* ws    = (float*)d_ws;
    ushort* xbf   = (ushort*)ws;                // 32P bf16 (16P f32)
    ushort* panbf = (ushort*)(ws + 16 * P);     // 32P bf16
    ushort* xnh   = (ushort*)(ws + 32 * P);     // 64P bf16 NHWC (32P f32)
    ushort* f2nh  = (ushort*)(ws + 64 * P);     // 32P bf16 (16P f32)
    float* W     = ws + 80 * P;                 // weight tables
    float* aue_wt = W;
    float* s1w1t  = W + 2304;
    float* s1w2t  = W + 6400;
    float* s2w1t  = W + 10496;
    float* s2w2t  = W + 14592;
    float* mw     = W + 18688;
    ushort* wub   = (ushort*)(W + 21248);
    ushort* wbfu  = wub;
    ushort* w2bf1 = wub + 18432;
    ushort* w2bf2 = wub + 36864;

    dim3 blk(256);

    setup_k<<<dim3(812), blk, 0, stream>>>(F1, pan, xbf, panbf,
                                           ue_conv_w, ue_aue_w, ua1_w, ua2_w,
                                           spe1_w1, spe1_w2, spe2_w1, spe2_w2,
                                           conv1_w, conv2_w, masks_u, ue_out_w, W, wub);

    // x = conv3x3(F_1; 32->64) via MFMA, NHWC bf16 out
    conv_ue_mfma<<<dim3(1024), blk, 0, stream>>>(xbf, wbfu, ue_conv_b, xnh);
    // Fused head: AU + EU + MEAN
    head_k<<<dim3(1024), blk, 0, stream>>>(xnh, aue_wt, ue_aue_b, mw, ue_out_b, ms,
                                           AU, EU, MEAN);

    // ---- uaconv 1 (U = EU, inputs F1 || pan) + folded conv1 -> f2 bf16 ----
    ua_fused_k<0><<<dim3(1024), blk, 0, stream>>>(
        EU, 0,
        spa1_w0, spa1_b0, spa1_w1, spa1_b1, spa1_w2, spa1_b2,
        spe1_w0, spe1_b0, s1w1t, spe1_b1, s1w2t, spe1_b2,
        xbf, panbf, w2bf1, conv1_b, nullptr, f2nh);

    // ---- uaconv 2 (U = 1-EU, inputs F1 || F_2) + folded conv2 -> FOUT ----
    ua_fused_k<1><<<dim3(1024), blk, 0, stream>>>(
        EU, 1,
        spa2_w0, spa2_b0, spa2_w1, spa2_b1, spa2_w2, spa2_b2,
        spe2_w0, spe2_b0, s2w1t, spe2_b1, s2w2t, spe2_b2,
        xbf, f2nh, w2bf2, conv2_b, FOUT, nullptr);
}

// Round 11
// 113.671 us; speedup vs baseline: 1.4918x; 1.1733x over previous
//
#include <hip/hip_runtime.h>
#include <hip/hip_bf16.h>
#include <math.h>
#include <string.h>

#define P 65536   // H*W
#define HH 256
#define WW 256

typedef __attribute__((ext_vector_type(8))) short bf16x8;
typedef __attribute__((ext_vector_type(4))) float f32x4;

__device__ __forceinline__ float fast_sigmoid(float v) {
    return 1.f / (1.f + __expf(-v));
}
__device__ __forceinline__ float fast_tanh(float a) {
    a = fminf(fmaxf(a, -10.f), 10.f);
    float t = __expf(2.f * a);
    return (t - 1.f) / (t + 1.f);
}
__device__ __forceinline__ ushort f2bf(float f) {
    unsigned u = __float_as_uint(f);
    unsigned r = (u + 0x7fffu + ((u >> 16) & 1u)) >> 16;
    return (ushort)r;
}
__device__ __forceinline__ unsigned pack_bf2(float a, float b) {
    __hip_bfloat162 h = __float22bfloat162_rn(make_float2(a, b));
    unsigned u;
    memcpy(&u, &h, 4);
    return u;
}

// ---------------------------------------------------------------------------
// setup_k: blocks [0,512) convert F1/pan -> NHWC bf16; blocks [512,875) prep.
// Float region W: [0,2304) aue_wt; [18688,21248) mw (middle regions legacy).
// ushort wub: [0,18432) wbfu; [18432,36864) w2bf1; [36864,55296) w2bf2;
//   [55296,71680) spe MFMA B-frags: 4 mats (s1w1,s1w2,s2w1,s2w2) x 4096,
//   frag idx = ct*1024 + kk*512 + n*32 + c  -> src[(ct*16+n)*64 + kk*32 + c]
__global__ __launch_bounds__(256) void setup_k(
        const float* __restrict__ F1, const float* __restrict__ pan,
        ushort* __restrict__ xbf, ushort* __restrict__ panbf,
        const float* __restrict__ ue_w, const float* __restrict__ aue_w,
        const float* __restrict__ ua1, const float* __restrict__ ua2,
        const float* __restrict__ s1w1, const float* __restrict__ s1w2,
        const float* __restrict__ s2w1, const float* __restrict__ s2w2,
        const float* __restrict__ cw1, const float* __restrict__ cw2,
        const float* __restrict__ masks_u, const float* __restrict__ w4,
        float* __restrict__ W, ushort* __restrict__ wub) {
    const int b = blockIdx.x;
    if (b < 512) {
        int idx = b * 256 + threadIdx.x;
        const float* src = (idx < P) ? F1 : pan;
        ushort* dst = (idx < P) ? xbf : panbf;
        int p = idx & (P - 1);
        unsigned pk[16];
        #pragma unroll
        for (int c = 0; c < 16; ++c) {
            float a = src[(2 * c) * P + p];
            float bb = src[(2 * c + 1) * P + p];
            pk[c] = (unsigned)f2bf(a) | ((unsigned)f2bf(bb) << 16);
        }
        uint4* d4 = (uint4*)(dst + (size_t)p * 32);
        #pragma unroll
        for (int q = 0; q < 4; ++q)
            d4[q] = make_uint4(pk[4 * q], pk[4 * q + 1], pk[4 * q + 2], pk[4 * q + 3]);
        return;
    }
    int i = (b - 512) * 256 + threadIdx.x;
    if (i < 2304) {                        // aue_w (co4, ci64, 9) -> [ci][k][co]
        int ci = i / 36, r = i % 36, k = r >> 2, co = r & 3;
        W[i] = aue_w[co * 576 + ci * 9 + k];
    } else if (i < 18688) {
        // legacy region unused
    } else if (i < 21248) {                // mw[t][o][c]
        int j = i - 18688;
        int t = j >> 8, o = (j >> 6) & 3, c = j & 63;
        W[i] = (masks_u[t * 64 + c] < 0.8f) ? w4[o * 64 + c] : 0.f;
    } else if (i < 39680) {                // wbfu
        int j = i - 21248;
        int ct = j / 4608, r1 = j % 4608;
        int kp = r1 / 512, r2 = r1 % 512;
        int n = r2 >> 5, ci = r2 & 31;
        wub[j] = f2bf(ue_w[(ct * 16 + n) * 288 + ci * 9 + kp]);
    } else if (i < 58112) {                // w2bf1 = cw1 @ ua1
        int j = i - 39680;
        int mo = j / 576, K = j % 576, k = K >> 6, n = K & 63;
        float s = 0.f;
        for (int m = 0; m < 32; ++m)
            s += cw1[mo * 32 + m] * ua1[m * 576 + n * 9 + k];
        wub[18432 + j] = f2bf(s);
    } else if (i < 76544) {                // w2bf2 = cw2 @ ua2
        int j = i - 58112;
        int mo = j / 576, K = j % 576, k = K >> 6, n = K & 63;
        float s = 0.f;
        for (int m = 0; m < 32; ++m)
            s += cw2[mo * 32 + m] * ua2[m * 576 + n * 9 + k];
        wub[36864 + j] = f2bf(s);
    } else if (i < 92928) {                // spe MFMA B-frags
        int j = i - 76544;
        int mat = j >> 12;                 // 0..3
        int r = j & 4095;
        int ct = r >> 10, kk = (r >> 9) & 1, n = (r >> 5) & 15, c = r & 31;
        const float* src = (mat == 0) ? s1w1 : (mat == 1) ? s1w2
                         : (mat == 2) ? s2w1 : s2w2;
        wub[55296 + j] = f2bf(src[(ct * 16 + n) * 64 + kk * 32 + c]);
    }
}

// ---------------------------------------------------------------------------
// ue conv (32->64, 3x3, pad=1) as MFMA implicit GEMM. Output: NHWC bf16.
__global__ __launch_bounds__(256) void conv_ue_mfma(
        const ushort* __restrict__ xbf, const ushort* __restrict__ wbfu,
        const float* __restrict__ bias, ushort* __restrict__ xnh) {
    __shared__ float tls[4][272];
    const int tid  = threadIdx.x;
    const int lane = tid & 63;
    const int wv   = __builtin_amdgcn_readfirstlane(tid >> 6);
    const int lrow = lane & 15;
    const int kg   = lane >> 4;

    bf16x8 zf;
    #pragma unroll
    for (int z = 0; z < 8; ++z) zf[z] = 0;

    bf16x8 Bf[9];
    const ushort* wb = wbfu + wv * 4608;
    #pragma unroll
    for (int kp = 0; kp < 9; ++kp)
        Bf[kp] = *(const bf16x8*)(wb + kp * 512 + lrow * 32 + kg * 8);

    const float bco = bias[wv * 16 + lrow];
    float* tw = tls[wv];

    for (int si = 0; si < 4; ++si) {
        const int s   = blockIdx.x * 4 + si;
        const int row = s >> 4;
        const int cb  = (s & 15) << 4;
        const int pb  = s << 4;
        f32x4 acc = {bco, bco, bco, bco};
        #pragma unroll
        for (int dh = -1; dh <= 1; ++dh) {
            if ((unsigned)(row + dh) >= 256u) continue;
            #pragma unroll
            for (int dw = -1; dw <= 1; ++dw) {
                const bool kill = (dw == -1 && cb == 0 && lrow == 0) ||
                                  (dw == 1 && cb == 240 && lrow == 15);
                const int apx = kill ? pb : (pb + dh * 256 + dw + lrow);
                bf16x8 Af = *(const bf16x8*)(xbf + (size_t)apx * 32 + kg * 8);
                if (kill) Af = zf;
                acc = __builtin_amdgcn_mfma_f32_16x16x32_bf16(
                          Af, Bf[(dh + 1) * 3 + (dw + 1)], acc, 0, 0, 0);
            }
        }
        #pragma unroll
        for (int j = 0; j < 4; ++j)
            tw[(kg * 4 + j) * 17 + lrow] = acc[j];
        asm volatile("s_waitcnt lgkmcnt(0)" ::: "memory");
        {
            const float* rp = tw + lrow * 17;
            unsigned o[8];
            #pragma unroll
            for (int q = 0; q < 8; ++q)
                o[q] = pack_bf2(rp[2 * q], rp[2 * q + 1]);
            ushort* dst = xnh + (size_t)(pb + lrow) * 64 + wv * 16;
            *(uint4*)dst       = make_uint4(o[0], o[1], o[2], o[3]);
            *(uint4*)(dst + 8) = make_uint4(o[4], o[5], o[6], o[7]);
        }
        asm volatile("s_waitcnt lgkmcnt(0)" ::: "memory");
    }
}

// ---------------------------------------------------------------------------
// Fused head: AU = sigmoid(conv3x3(x;64->4)), EU/MEAN = var/mean of xs.
__global__ __launch_bounds__(256) void head_k(
        const ushort* __restrict__ xnh, const float* __restrict__ aue_wt,
        const float* __restrict__ aue_b, const float* __restrict__ mw,
        const float* __restrict__ b4, const float* __restrict__ msin,
        float* __restrict__ AU, float* __restrict__ EU, float* __restrict__ MEAN) {
    __shared__ float cs[64][65];
    __shared__ float pr[4][4][64];
    const int tid = threadIdx.x;
    const int pxg = tid & 63;
    const int g   = __builtin_amdgcn_readfirstlane(tid >> 6);
    const int p   = blockIdx.x * 64 + pxg;
    const int h = p >> 8, x0 = p & 255;
    const int cib = g * 16;

    float pa[4] = {0.f, 0.f, 0.f, 0.f};
    float cv[16];
    #pragma unroll
    for (int k = 0; k < 9; ++k) {
        const int dh = k / 3 - 1, dw = k % 3 - 1;
        if ((unsigned)(h + dh) >= 256u) continue;
        const bool kill = (dw == -1 && x0 == 0) || (dw == 1 && x0 == 255);
        const int pxe = kill ? p : (p + dh * 256 + dw);
        const ushort* sp = xnh + (size_t)pxe * 64 + cib;
        uint4 ra = *(const uint4*)sp;
        uint4 rb = *(const uint4*)(sp + 8);
        unsigned rr[8] = {ra.x, ra.y, ra.z, ra.w, rb.x, rb.y, rb.z, rb.w};
        if (kill) {
            #pragma unroll
            for (int q = 0; q < 8; ++q) rr[q] = 0;
        }
        float f[16];
        #pragma unroll
        for (int q = 0; q < 8; ++q) {
            f[2 * q]     = __uint_as_float(rr[q] << 16);
            f[2 * q + 1] = __uint_as_float(rr[q] & 0xffff0000u);
        }
        if (k == 4) {
            #pragma unroll
            for (int ci = 0; ci < 16; ++ci) cv[ci] = f[ci];
        }
        #pragma unroll
        for (int ci = 0; ci < 16; ++ci) {
            const float* wp = aue_wt + (cib + ci) * 36 + k * 4;
            #pragma unroll
            for (int co = 0; co < 4; ++co)
                pa[co] = fmaf(f[ci], wp[co], pa[co]);
        }
    }
    #pragma unroll
    for (int co = 0; co < 4; ++co) pr[co][g][pxg] = pa[co];
    #pragma unroll
    for (int ci = 0; ci < 16; ++ci) cs[pxg][cib + ci] = cv[ci];
    __syncthreads();

    {
        float s = aue_b[g] + pr[g][0][pxg] + pr[g][1][pxg]
                           + pr[g][2][pxg] + pr[g][3][pxg];
        AU[g * P + p] = fast_sigmoid(s);
    }

    float xv[64];
    #pragma unroll
    for (int c = 0; c < 64; ++c) xv[c] = cs[pxg][c];
    float msv = msin[g * P + p];
    float bo  = b4[g];
    float vals[10];
    float s = 0.f;
    #pragma unroll
    for (int t = 0; t < 10; ++t) {
        float a = bo;
        const float* mwp = mw + t * 256 + g * 64;
        #pragma unroll
        for (int c = 0; c < 64; ++c) a = fmaf(mwp[c], xv[c], a);
        float v = fast_tanh(a) + msv;
        vals[t] = v;
        s += v;
    }
    float m = s * 0.1f;
    MEAN[g * P + p] = m;
    float var = 0.f;
    #pragma unroll
    for (int t = 0; t < 10; ++t) { float d = vals[t] - m; var = fmaf(d, d, var); }
    EU[g * P + p] = var * (1.0f / 9.0f);
}

// ---------------------------------------------------------------------------
// Fully fused uaconv v2: spe MLP on MFMA.
// ping/pong: bf16 [64 px][72] (pad-72 rows, 144B, 16B-aligned).
// phase 1: h1(VALU, 16ci/thread) -> ping; L2 MFMA -> pong; L3 MFMA+sigmoid
// -> spec into ping (wave-local rows, no barrier); spa chain (VALU) -> spat_l.
// phase 2: einsum MFMA (unchanged); epilogue tile unions pong.
// OUTMODE 0: f2 NHWC bf16; OUTMODE 1: FOUT f32 CHW.
template<int OUTMODE>
__global__ __launch_bounds__(256) void ua_fused_k(
        const float* __restrict__ U, int flip,
        const float* __restrict__ aw0, const float* __restrict__ ab0,
        const float* __restrict__ aw1, const float* __restrict__ ab1,
        const float* __restrict__ aw2, const float* __restrict__ ab2,
        const float* __restrict__ pw0, const float* __restrict__ pb0,
        const float* __restrict__ pb1, const float* __restrict__ pb2,
        const ushort* __restrict__ wspe,
        const ushort* __restrict__ xa, const ushort* __restrict__ xb,
        const ushort* __restrict__ w2bf, const float* __restrict__ cb,
        float* __restrict__ outf, ushort* __restrict__ outh) {
    __shared__ __align__(16) ushort ping[64 * 72];   // 9216 B
    __shared__ __align__(16) ushort pong[64 * 72];   // 9216 B (epilogue unions)
    __shared__ float spat_l[9][64];                  // 2.25 KB
    const int tid = threadIdx.x;
    const int pxg = tid & 63;
    const int g   = __builtin_amdgcn_readfirstlane(tid >> 6);
    const int cib = g * 16;
    const int p   = blockIdx.x * 64 + pxg;
    const int h = p >> 8, x0 = p & 255;
    const int lane = tid & 63;
    const int lrow = lane & 15;
    const int kg   = lane >> 4;

    // spe B-frags: [layer2][ct4][kk2], lane: n=lrow, k-chunk=kg
    bf16x8 Wf[2][4][2];
    #pragma unroll
    for (int ly = 0; ly < 2; ++ly)
        #pragma unroll
        for (int ct = 0; ct < 4; ++ct)
            #pragma unroll
            for (int kk = 0; kk < 2; ++kk)
                Wf[ly][ct][kk] = *(const bf16x8*)(wspe + ly * 4096 +
                                     ct * 1024 + kk * 512 + lrow * 32 + kg * 8);

    // ---- h1 (K=4, VALU), 16 ci per thread -> ping[px][ci] ----
    {
        float u[4];
        #pragma unroll
        for (int ci = 0; ci < 4; ++ci) {
            float v = U[ci * P + p];
            u[ci] = flip ? 1.f - v : v;
        }
        unsigned* prow = (unsigned*)ping + (pxg * 72 + cib) / 2;
        #pragma unroll
        for (int cl = 0; cl < 8; ++cl) {
            int c0 = cib + 2 * cl, c1 = c0 + 1;
            float s0 = pb0[c0], s1 = pb0[c1];
            #pragma unroll
            for (int k = 0; k < 4; ++k) {
                s0 = fmaf(u[k], pw0[c0 * 4 + k], s0);
                s1 = fmaf(u[k], pw0[c1 * 4 + k], s1);
            }
            prow[cl] = pack_bf2(fmaxf(s0, 0.f), fmaxf(s1, 0.f));
        }
    }
    __syncthreads();

    // ---- layer 2 MFMA: pong = relu(ping @ W1 + b1), wave-local rows ----
    #pragma unroll
    for (int ct = 0; ct < 4; ++ct) {
        f32x4 a = {0.f, 0.f, 0.f, 0.f};
        #pragma unroll
        for (int kk = 0; kk < 2; ++kk) {
            bf16x8 A = *(const bf16x8*)&ping[(g * 16 + lrow) * 72 + kk * 32 + kg * 8];
            a = __builtin_amdgcn_mfma_f32_16x16x32_bf16(A, Wf[0][ct][kk], a, 0, 0, 0);
        }
        float b = pb1[ct * 16 + lrow];
        #pragma unroll
        for (int j = 0; j < 4; ++j)
            pong[(g * 16 + kg * 4 + j) * 72 + ct * 16 + lrow] = f2bf(fmaxf(a[j] + b, 0.f));
    }
    // ---- layer 3 MFMA: spec = sigmoid(pong @ W2 + b2) -> ping ----
    asm volatile("s_waitcnt lgkmcnt(0)" ::: "memory");
    #pragma unroll
    for (int ct = 0; ct < 4; ++ct) {
        f32x4 a = {0.f, 0.f, 0.f, 0.f};
        #pragma unroll
        for (int kk = 0; kk < 2; ++kk) {
            bf16x8 A = *(const bf16x8*)&pong[(g * 16 + lrow) * 72 + kk * 32 + kg * 8];
            a = __builtin_amdgcn_mfma_f32_16x16x32_bf16(A, Wf[1][ct][kk], a, 0, 0, 0);
        }
        float b = pb2[ct * 16 + lrow];
        #pragma unroll
        for (int j = 0; j < 4; ++j)
            ping[(g * 16 + kg * 4 + j) * 72 + ct * 16 + lrow] =
                f2bf(fast_sigmoid(a[j] + b));
    }

    // ---- spa chain (VALU) -> spat_l ----
    {
        float uh[4][9];
        #pragma unroll
        for (int ci = 0; ci < 4; ++ci) {
            const float* up = U + ci * P;
            #pragma unroll
            for (int kh = 0; kh < 3; ++kh) {
                int hh = h + kh - 1;
                bool hok = (unsigned)hh < 256u;
                #pragma unroll
                for (int kw = 0; kw < 3; ++kw) {
                    int wx = x0 + kw - 1;
                    bool ok = hok && (unsigned)wx < 256u;
                    float v = ok ? up[hh * WW + wx] : 0.f;
                    if (flip && ok) v = 1.f - v;
                    uh[ci][kh * 3 + kw] = v;
                }
            }
        }
        float a1[9];
        #pragma unroll
        for (int co = 0; co < 9; ++co) {
            float s = ab0[co];
            #pragma unroll
            for (int ci = 0; ci < 4; ++ci)
                #pragma unroll
                for (int k = 0; k < 9; ++k)
                    s = fmaf(uh[ci][k], aw0[co * 36 + ci * 9 + k], s);
            a1[co] = fmaxf(s, 0.f);
        }
        float a2[9];
        #pragma unroll
        for (int co = 0; co < 9; ++co) {
            float s = ab1[co];
            #pragma unroll
            for (int ci = 0; ci < 9; ++ci) s = fmaf(a1[ci], aw1[co * 9 + ci], s);
            a2[co] = fmaxf(s, 0.f);
        }
        #pragma unroll
        for (int cq = 0; cq < 3; ++cq) {
            const int co = g + cq * 4;
            if (co < 9) {
                float s = ab2[co];
                #pragma unroll
                for (int ci = 0; ci < 9; ++ci) s = fmaf(a2[ci], aw2[co * 9 + ci], s);
                spat_l[co][pxg] = fast_sigmoid(s);
            }
        }
    }
    __syncthreads();   // spat_l cross-wave; spec rows are wave-local

    // ================= phase 2: MFMA einsum =================
    const int wv   = g;
    const int s    = blockIdx.x * 4 + wv;
    const int row  = s >> 4;
    const int c16  = s & 15;
    const int pb   = s << 4;
    const int px   = pb + lrow;
    const int pxl  = wv * 16 + lrow;    // local pixel index

    float sl[8], sh[8];
    {
        const unsigned* sp = (const unsigned*)&ping[pxl * 72 + kg * 8];
        #pragma unroll
        for (int q = 0; q < 4; ++q) {
            unsigned uu = sp[q];
            sl[2 * q]     = __uint_as_float(uu << 16);
            sl[2 * q + 1] = __uint_as_float(uu & 0xffff0000u);
        }
        const unsigned* sp2 = (const unsigned*)&ping[pxl * 72 + 32 + kg * 8];
        #pragma unroll
        for (int q = 0; q < 4; ++q) {
            unsigned uu = sp2[q];
            sh[2 * q]     = __uint_as_float(uu << 16);
            sh[2 * q + 1] = __uint_as_float(uu & 0xffff0000u);
        }
    }
    const ushort* b0p = w2bf + lrow * 576 + kg * 8;
    const ushort* b1p = w2bf + (16 + lrow) * 576 + kg * 8;

    f32x4 acc0 = {0.f, 0.f, 0.f, 0.f};
    f32x4 acc1 = {0.f, 0.f, 0.f, 0.f};

    #pragma unroll
    for (int k = 0; k < 9; ++k) {
        const int dh = k / 3 - 1, dw = k % 3 - 1;
        if ((unsigned)(row + dh) >= 256u) continue;   // wave-uniform skip
        const bool kill = (dw == -1 && c16 == 0 && lrow == 0) ||
                          (dw == 1 && c16 == 15 && lrow == 15);
        float stk = spat_l[k][pxl];
        if (kill) stk = 0.f;
        const int pxe = kill ? px : (px + dh * 256 + dw);
        #pragma unroll
        for (int par = 0; par < 2; ++par) {
            const ushort* src = (par == 0) ? (xa + (size_t)pxe * 32 + kg * 8)
                                           : (xb + (size_t)pxe * 32 + kg * 8);
            uint4 raw = *(const uint4*)src;
            const float* ss = par ? sh : sl;
            unsigned rr[4] = {raw.x, raw.y, raw.z, raw.w};
            union { unsigned u[4]; bf16x8 v; } af;
            #pragma unroll
            for (int q = 0; q < 4; ++q) {
                float e0 = __uint_as_float(rr[q] << 16)          * (ss[2 * q] * stk);
                float e1 = __uint_as_float(rr[q] & 0xffff0000u)  * (ss[2 * q + 1] * stk);
                af.u[q] = pack_bf2(e0, e1);
            }
            const int ki = k * 2 + par;
            bf16x8 bf0 = *(const bf16x8*)(b0p + ki * 32);
            bf16x8 bf1 = *(const bf16x8*)(b1p + ki * 32);
            acc0 = __builtin_amdgcn_mfma_f32_16x16x32_bf16(af.v, bf0, acc0, 0, 0, 0);
            acc1 = __builtin_amdgcn_mfma_f32_16x16x32_bf16(af.v, bf1, acc1, 0, 0, 0);
        }
    }

    const float cb0 = cb[lrow], cb1 = cb[16 + lrow];
    float* tw = (float*)pong + wv * 560;
    #pragma unroll
    for (int j = 0; j < 4; ++j) {
        float y0 = acc0[j] + cb0; y0 = y0 > 0.f ? y0 : 0.2f * y0;
        float y1 = acc1[j] + cb1; y1 = y1 > 0.f ? y1 : 0.2f * y1;
        tw[(kg * 4 + j) * 35 + lrow] = y0;
        tw[(kg * 4 + j) * 35 + 16 + lrow] = y1;
    }
    asm volatile("s_waitcnt lgkmcnt(0)" ::: "memory");
    if constexpr (OUTMODE == 0) {
        const float* rp = tw + lrow * 35 + kg * 8;
        unsigned o[4];
        #pragma unroll
        for (int q = 0; q < 4; ++q)
            o[q] = pack_bf2(rp[2 * q], rp[2 * q + 1]);
        *(uint4*)(outh + (size_t)(pb + lrow) * 32 + kg * 8) =
            make_uint4(o[0], o[1], o[2], o[3]);
    } else {
        #pragma unroll
        for (int it = 0; it < 8; ++it) {
            const int mo = kg * 8 + it;
            outf[mo * P + pb + lrow] = tw[lrow * 35 + mo];
        }
    }
    asm volatile("s_waitcnt lgkmcnt(0)" ::: "memory");
}

// ---------------------------------------------------------------------------
extern "C" void kernel_launch(void* const* d_in, const int* in_sizes, int n_in,
                              void* d_out, int out_size, void* d_ws, size_t ws_size,
                              hipStream_t stream) {
    const float* F1        = (const float*)d_in[0];
    const float* ms        = (const float*)d_in[1];
    const float* pan       = (const float*)d_in[2];
    const float* masks_u   = (const float*)d_in[3];
    const float* ue_conv_w = (const float*)d_in[4];
    const float* ue_conv_b = (const float*)d_in[5];
    const float* ue_out_w  = (const float*)d_in[6];
    const float* ue_out_b  = (const float*)d_in[7];
    const float* ue_aue_w  = (const float*)d_in[8];
    const float* ue_aue_b  = (const float*)d_in[9];
    const float* conv1_w   = (const float*)d_in[10];
    const float* conv1_b   = (const float*)d_in[11];
    const float* conv2_w   = (const float*)d_in[12];
    const float* conv2_b   = (const float*)d_in[13];
    const float* spa1_w0 = (const float*)d_in[14];
    const float* spa1_b0 = (const float*)d_in[15];
    const float* spa1_w1 = (const float*)d_in[16];
    const float* spa1_b1 = (const float*)d_in[17];
    const float* spa1_w2 = (const float*)d_in[18];
    const float* spa1_b2 = (const float*)d_in[19];
    const float* spe1_w0 = (const float*)d_in[20];
    const float* spe1_b0 = (const float*)d_in[21];
    const float* spe1_w1 = (const float*)d_in[22];
    const float* spe1_b1 = (const float*)d_in[23];
    const float* spe1_w2 = (const float*)d_in[24];
    const float* spe1_b2 = (const float*)d_in[25];
    const float* ua1_w   = (const float*)d_in[26];
    const float* spa2_w0 = (const float*)d_in[27];
    const float* spa2_b0 = (const float*)d_in[28];
    const float* spa2_w1 = (const float*)d_in[29];
    const float* spa2_b1 = (const float*)d_in[30];
    const float* spa2_w2 = (const float*)d_in[31];
    const float* spa2_b2 = (const float*)d_in[32];
    const float* spe2_w0 = (const float*)d_in[33];
    const float* spe2_b0 = (const float*)d_in[34];
    const float* spe2_w1 = (const float*)d_in[35];
    const float* spe2_b1 = (const float*)d_in[36];
    const float* spe2_w2 = (const float*)d_in[37];
    const float* spe2_b2 = (const float*)d_in[38];
    const float* ua2_w   = (const float*)d_in[39];

    float* out  = (float*)d_out;
    float* AU   = out;             // 4*P
    float* EU   = out + 4 * P;     // 4*P
    float* MEAN = out + 8 * P;     // 4*P
    float* FOUT = out + 12 * P;    // 32*P

    float* ws    = (float*)d_ws;
    ushort* xbf   = (ushort*)ws;                // 32P bf16 (16P f32)
    ushort* panbf = (ushort*)(ws + 16 * P);     // 32P bf16
    ushort* xnh   = (ushort*)(ws + 32 * P);     // 64P bf16 NHWC (32P f32)
    ushort* f2nh  = (ushort*)(ws + 64 * P);     // 32P bf16 (16P f32)
    float* W     = ws + 80 * P;                 // weight tables
    float* aue_wt = W;
    float* mw     = W + 18688;
    ushort* wub   = (ushort*)(W + 21248);
    ushort* wbfu  = wub;
    ushort* w2bf1 = wub + 18432;
    ushort* w2bf2 = wub + 36864;
    ushort* wspe1 = wub + 55296;     // s1w1,s1w2 frags (8192)
    ushort* wspe2 = wub + 63488;     // s2w1,s2w2 frags (8192)

    dim3 blk(256);

    setup_k<<<dim3(875), blk, 0, stream>>>(F1, pan, xbf, panbf,
                                           ue_conv_w, ue_aue_w, ua1_w, ua2_w,
                                           spe1_w1, spe1_w2, spe2_w1, spe2_w2,
                                           conv1_w, conv2_w, masks_u, ue_out_w, W, wub);

    // x = conv3x3(F_1; 32->64) via MFMA, NHWC bf16 out
    conv_ue_mfma<<<dim3(1024), blk, 0, stream>>>(xbf, wbfu, ue_conv_b, xnh);
    // Fused head: AU + EU + MEAN
    head_k<<<dim3(1024), blk, 0, stream>>>(xnh, aue_wt, ue_aue_b, mw, ue_out_b, ms,
                                           AU, EU, MEAN);

    // ---- uaconv 1 (U = EU, inputs F1 || pan) + folded conv1 -> f2 bf16 ----
    ua_fused_k<0><<<dim3(1024), blk, 0, stream>>>(
        EU, 0,
        spa1_w0, spa1_b0, spa1_w1, spa1_b1, spa1_w2, spa1_b2,
        spe1_w0, spe1_b0, spe1_b1, spe1_b2, wspe1,
        xbf, panbf, w2bf1, conv1_b, nullptr, f2nh);

    // ---- uaconv 2 (U = 1-EU, inputs F1 || F_2) + folded conv2 -> FOUT ----
    ua_fused_k<1><<<dim3(1024), blk, 0, stream>>>(
        EU, 1,
        spa2_w0, spa2_b0, spa2_w1, spa2_b1, spa2_w2, spa2_b2,
        spe2_w0, spe2_b0, spe2_b1, spe2_b2, wspe2,
        xbf, f2nh, w2bf2, conv2_b, FOUT, nullptr);
}